// Round 16
// baseline (79.667 us; speedup 1.0000x reference)
//
#include <hip/hip_runtime.h>
#include <cstdint>
#include <cstddef>

// ---------------------------------------------------------------------------
// CosineDistance via exact int8 reconstruction:
//   ref's 9 bit-slice GEMMs == qx (int8) @ qw^T (int8), dequant, 1 - cos.
// R13 (best, 77.7us): 256x128 tile, 2 blocks/CU, counted vmcnt(6).
// R14: NT stores -12us regression (reverted); counters exonerated staging
//      BW (FETCH 67.6MB ~ 10us) -- gemm is issue/latency-bound.
// R15: XCD-stripe ~neutral (reverted to R13 swizzle).
// R16: LDS-TRANSPOSE EPILOGUE. Old: 128 scalar dword stores/thread (64B
// segments, uncovered end burst, half the kernel's VMEM instrs). New:
// acc -> LDS (4 chunks of 64 rows x 128 cols, stride 132) -> 32
// dwordx4/thread with 512B-contiguous rows. lgkm-only chunk barriers
// keep prior chunks' stores in flight. Single change vs R13.
// ---------------------------------------------------------------------------

#define D_COLS 1024
#define M_ROWS 4096   // x rows
#define N_ROWS 8192   // weight rows

using i32x4 = __attribute__((ext_vector_type(4))) int;

__device__ __forceinline__ void gload_lds16(const void* g, void* lds) {
  __builtin_amdgcn_global_load_lds(
      (const __attribute__((address_space(1))) uint32_t*)g,
      (__attribute__((address_space(3))) uint32_t*)lds, 16, 0, 0);
}

// One block per row (x rows 0..4095, w rows 4096..12287):
// invnorm[row] = 1/||row||, rmax[row] = max|row| * invnorm. No atomics.
__global__ __launch_bounds__(256) void rownorm_kernel(
    const float* __restrict__ x, const float* __restrict__ w,
    float* __restrict__ invnorm, float* __restrict__ rmax) {
  const int row = blockIdx.x;
  const float* a = (row < M_ROWS) ? x + (size_t)row * D_COLS
                                  : w + (size_t)(row - M_ROWS) * D_COLS;
  const float4 v = ((const float4*)a)[threadIdx.x];
  float ss = v.x * v.x + v.y * v.y + v.z * v.z + v.w * v.w;
  float mx = fmaxf(fmaxf(fabsf(v.x), fabsf(v.y)), fmaxf(fabsf(v.z), fabsf(v.w)));
#pragma unroll
  for (int off = 32; off; off >>= 1) {
    ss += __shfl_down(ss, off, 64);
    mx = fmaxf(mx, __shfl_down(mx, off, 64));
  }
  __shared__ float s_ss[4], s_mx[4];
  const int wave = threadIdx.x >> 6, lane = threadIdx.x & 63;
  if (lane == 0) { s_ss[wave] = ss; s_mx[wave] = mx; }
  __syncthreads();
  if (threadIdx.x == 0) {
    float tss = (s_ss[0] + s_ss[1]) + (s_ss[2] + s_ss[3]);
    float tmx = fmaxf(fmaxf(s_mx[0], s_mx[1]), fmaxf(s_mx[2], s_mx[3]));
    float inv = 1.0f / fmaxf(sqrtf(tss), 1e-12f);
    invnorm[row] = inv;
    rmax[row] = tmx * inv;
  }
}

// Single block: scales[0] = max(rmax[0:4096]), scales[1] = max(rmax[4096:12288])
__global__ __launch_bounds__(1024) void scale_reduce_kernel(
    const float* __restrict__ rmax, float* __restrict__ scales) {
  const int t = threadIdx.x;
  float mx = 0.f, mw = 0.f;
  for (int i = t; i < M_ROWS; i += 1024) mx = fmaxf(mx, rmax[i]);
  for (int i = t; i < N_ROWS; i += 1024) mw = fmaxf(mw, rmax[M_ROWS + i]);
#pragma unroll
  for (int off = 32; off; off >>= 1) {
    mx = fmaxf(mx, __shfl_down(mx, off, 64));
    mw = fmaxf(mw, __shfl_down(mw, off, 64));
  }
  __shared__ float smx[16], smw[16];
  const int wave = t >> 6, lane = t & 63;
  if (lane == 0) { smx[wave] = mx; smw[wave] = mw; }
  __syncthreads();
  if (t == 0) {
    float a = 0.f, b = 0.f;
#pragma unroll
    for (int i = 0; i < 16; ++i) { a = fmaxf(a, smx[i]); b = fmaxf(b, smw[i]); }
    scales[0] = a;
    scales[1] = b;
  }
}

// ---------------------------------------------------------------------------
// Quantize + transpose into the blocked GEMM image via LDS (validated).
// Slab (panel Q = row>>7, ks 0..15) = 8KB at (Q*16+ks)*512 uint4; inside:
// idx = ck*128 + row_local, ck = 16B-K-chunk 0..3 (global cc: ks=cc>>2,
// ck=cc&3). Coalesced reads, XOR-swizzled LDS, 256B-contiguous writes.
// ---------------------------------------------------------------------------
__global__ __launch_bounds__(256) void quant_transpose_kernel(
    const float* __restrict__ a, const float* __restrict__ invnorm,
    const float* __restrict__ scale, uint4* __restrict__ img) {
  __shared__ uint4 T[128][16];
  const int t = threadIdx.x;
  const int g = blockIdx.x & 3;          // cc group (16 cc's)
  const int Q = blockIdx.x >> 2;         // 128-row panel
  const float s = 127.0f / scale[0];

  const int cc_l = t & 15;
  const int tr = t >> 4;
#pragma unroll
  for (int rc = 0; rc < 8; ++rc) {
    const int rl = rc * 16 + tr;
    const int r = Q * 128 + rl;
    const float f = invnorm[r] * s;
    const float4* src = (const float4*)(a + (size_t)r * D_COLS + (g * 16 + cc_l) * 16);
    unsigned pk[4];
#pragma unroll
    for (int q = 0; q < 4; ++q) {
      const float4 v = src[q];
      const int q0 = (int)rintf(v.x * f), q1 = (int)rintf(v.y * f);
      const int q2 = (int)rintf(v.z * f), q3 = (int)rintf(v.w * f);
      pk[q] = (unsigned)(q0 & 0xff) | ((unsigned)(q1 & 0xff) << 8) |
              ((unsigned)(q2 & 0xff) << 16) | ((unsigned)(q3 & 0xff) << 24);
    }
    T[rl][cc_l ^ (rl & 15)] = make_uint4(pk[0], pk[1], pk[2], pk[3]);
  }
  __syncthreads();

  const int cc_w = g * 16 + (t >> 4);    // global cc 0..63
  const int rw = t & 15;
  uint4* dst = img + (size_t)(Q * 16 + (cc_w >> 2)) * 512 + (cc_w & 3) * 128;
#pragma unroll
  for (int i = 0; i < 8; ++i) {
    const int rl = i * 16 + rw;
    dst[rl] = T[rl][(t >> 4) ^ (rl & 15)];
  }
}

// ---------------------------------------------------------------------------
// int8 GEMM, 256x128 tile, 4 waves (wr=wave>>1, wc=wave&1), per-wave 128x64
// (acc[8][4] = 128 AGPR), 16 K-steps BK=64, ring-2 24KB bufs, counted
// vmcnt(6), setprio on MFMA. (R13 K-loop, byte-identical.)
//
// R16 epilogue: LDS transpose -> vectorized stores.
// 4 chunks of 64 rows x 128 cols (f32, stride 132 -> 528B rows, 16B-divis):
//   chunk c owned by waves with wr == c>>1; they ds_write their acc
//   m-groups (c&1)*4..+3 (16 lanes consecutive cols -> <=2-way banks).
//   lgkmcnt(0)+barrier; then ALL 256 threads read 8 float4 (contiguous
//   512B rows) and store 8 dwordx4 (512B-contiguous per out row).
//   Top-of-chunk barrier is lgkm-only: prior chunks' global stores
//   remain in flight (vm not drained).
// ---------------------------------------------------------------------------
__global__ __launch_bounds__(256, 2) void gemm_i8_kernel(
    const char* __restrict__ qx, const char* __restrict__ qw,
    const float* __restrict__ sx, const float* __restrict__ sw,
    float* __restrict__ out) {
  __shared__ __align__(16) char L[49152];
  const int t = threadIdx.x;
  const int wave = t >> 6, lane = t & 63;
  const int wr = wave >> 1, wc = wave & 1;
  const int rl = lane & 15, ko = lane >> 4;   // ko = 16B K-chunk 0..3

  const int fid = blockIdx.x;                  // 0..1023
  const int swz = (fid & 7) * 128 + (fid >> 3);
  const int bx = swz & 63;                     // col tile 0..63 (128 cols)
  const int by = swz >> 6;                     // row tile 0..15 (256 rows)

  const char* sa0 = qx + (size_t)(2 * by) * 16 * 8192;      // panel 2by
  const char* sa1 = qx + (size_t)(2 * by + 1) * 16 * 8192;  // panel 2by+1
  const char* sb0 = qw + (size_t)bx * 16 * 8192;

  i32x4 acc[8][4] = {};

#define ISSUE_HT(ks)                                                          \
  {                                                                           \
    const size_t so_ = (size_t)(ks) * 8192;                                   \
    char* d_ = L + ((ks) & 1) * 24576;                                        \
    gload_lds16(sa0 + so_ + wave * 2048 + lane * 16, d_ + wave * 2048);       \
    gload_lds16(sa0 + so_ + wave * 2048 + 1024 + lane * 16,                   \
                d_ + wave * 2048 + 1024);                                     \
    gload_lds16(sa1 + so_ + wave * 2048 + lane * 16, d_ + 8192 + wave * 2048);\
    gload_lds16(sa1 + so_ + wave * 2048 + 1024 + lane * 16,                   \
                d_ + 8192 + wave * 2048 + 1024);                              \
    gload_lds16(sb0 + so_ + wave * 2048 + lane * 16, d_ + 16384 + wave * 2048);\
    gload_lds16(sb0 + so_ + wave * 2048 + 1024 + lane * 16,                   \
                d_ + 16384 + wave * 2048 + 1024);                             \
  }

#define STEP(ks, VM)                                                          \
  {                                                                           \
    if ((ks) + 1 < 16) ISSUE_HT((ks) + 1);                                    \
    asm volatile("s_waitcnt vmcnt(" #VM ")" ::: "memory");                    \
    asm volatile("s_barrier" ::: "memory");                                   \
    const char* Ab_ = L + ((ks) & 1) * 24576 + wr * 8192;                     \
    const char* Bb_ = L + ((ks) & 1) * 24576 + 16384;                         \
    i32x4 af_[8], bf_[4];                                                     \
    _Pragma("unroll") for (int m_ = 0; m_ < 8; ++m_)                          \
      af_[m_] = *(const i32x4*)(Ab_ + (ko * 128 + m_ * 16 + rl) * 16);        \
    _Pragma("unroll") for (int n_ = 0; n_ < 4; ++n_)                          \
      bf_[n_] = *(const i32x4*)(Bb_ +                                         \
          (ko * 128 + wc * 64 + n_ * 16 + rl) * 16);                          \
    __builtin_amdgcn_s_setprio(1);                                            \
    _Pragma("unroll") for (int m_ = 0; m_ < 8; ++m_)                          \
      _Pragma("unroll") for (int n_ = 0; n_ < 4; ++n_)                        \
        acc[m_][n_] = __builtin_amdgcn_mfma_i32_16x16x64_i8(                  \
            af_[m_], bf_[n_], acc[m_][n_], 0, 0, 0);                          \
    __builtin_amdgcn_s_setprio(0);                                            \
    asm volatile("s_barrier" ::: "memory");                                   \
  }

  ISSUE_HT(0);

#pragma unroll 1
  for (int ks = 0; ks < 15; ++ks) STEP(ks, 6);
  STEP(15, 0);
#undef STEP
#undef ISSUE_HT

  // ---- vectorized epilogue via LDS transpose ----
  const float cs = sx[0] * sw[0] * (1.0f / 16129.0f);  // (sx/127)*(sw/127)
  const int rowBase = by * 256;
  const int colBase = bx * 128;
  float* T = (float*)L;                 // [64][132] f32 = 33792 B

#pragma unroll
  for (int c = 0; c < 4; ++c) {
    // LDS free for this chunk: my ds ops drained, barrier with all waves.
    asm volatile("s_waitcnt lgkmcnt(0)" ::: "memory");
    asm volatile("s_barrier" ::: "memory");
    if (wr == (c >> 1)) {
      // write my acc m-groups (c&1)*4 .. +3 into rows mm*16+ko*4+j
#pragma unroll
      for (int mm = 0; mm < 4; ++mm)
#pragma unroll
        for (int n = 0; n < 4; ++n)
#pragma unroll
          for (int j = 0; j < 4; ++j)
            T[(mm * 16 + ko * 4 + j) * 132 + wc * 64 + n * 16 + rl] =
                1.0f - (float)acc[(c & 1) * 4 + mm][n][j] * cs;
    }
    asm volatile("s_waitcnt lgkmcnt(0)" ::: "memory");
    asm volatile("s_barrier" ::: "memory");
    // all threads: read contiguous rows, store 512B-contiguous runs
#pragma unroll
    for (int i = 0; i < 8; ++i) {
      const int idx = i * 256 + t;       // 0..2047
      const int row = idx >> 5;          // 0..63
      const int c4 = idx & 31;           // float4 within row
      const float4 v = *(const float4*)&T[row * 132 + c4 * 4];
      *(float4*)&out[(size_t)(rowBase + c * 64 + row) * N_ROWS + colBase + c4 * 4] = v;
    }
  }
}

extern "C" void kernel_launch(void* const* d_in, const int* in_sizes, int n_in,
                              void* d_out, int out_size, void* d_ws, size_t ws_size,
                              hipStream_t stream) {
  const float* x = (const float*)d_in[0];   // [4096, 1024]
  const float* w = (const float*)d_in[1];   // [8192, 1024]
  float* out = (float*)d_out;               // [4096, 8192]

  char* ws = (char*)d_ws;
  char* qx = ws;                                        // 4 MB blocked image
  char* qw = ws + (size_t)M_ROWS * D_COLS;              // 8 MB blocked image
  float* invnorm = (float*)(ws + (size_t)(M_ROWS + N_ROWS) * D_COLS);  // [12288]
  float* rmax = invnorm + (M_ROWS + N_ROWS);            // [12288]
  float* scales = rmax + (M_ROWS + N_ROWS);             // [0]=sx, [1]=sw

  rownorm_kernel<<<M_ROWS + N_ROWS, 256, 0, stream>>>(x, w, invnorm, rmax);
  scale_reduce_kernel<<<1, 1024, 0, stream>>>(rmax, scales);

  quant_transpose_kernel<<<M_ROWS / 128 * 4, 256, 0, stream>>>(
      x, invnorm, &scales[0], (uint4*)qx);
  quant_transpose_kernel<<<N_ROWS / 128 * 4, 256, 0, stream>>>(
      w, invnorm + M_ROWS, &scales[1], (uint4*)qw);

  gemm_i8_kernel<<<dim3(1024), 256, 0, stream>>>(qx, qw, &scales[0], &scales[1], out);
}

// Round 17
// 73.062 us; speedup vs baseline: 1.0904x; 1.0904x over previous
//
#include <hip/hip_runtime.h>
#include <cstdint>
#include <cstddef>

// ---------------------------------------------------------------------------
// CosineDistance via exact int8 reconstruction:
//   ref's 9 bit-slice GEMMs == qx (int8) @ qw^T (int8), dequant, 1 - cos.
// Best = R13 (77.7us): 256x128 tile, 2 blocks/CU, counted vmcnt(6).
// Elimination ledger R4-R16: staging coalescing fixed (real win R5);
// schedule x5, XCD swizzle, NT stores, vectorized epilogue: all neutral
// or worse. Serial-sum model: MFMA 17 + LDS 15 + stores 20 + staging 10
// = 62 ~= observed gemm 66 (barrier-lockstep serializes the pipes).
// R17: R13-exact gemm + FUSED single quant launch (the only unbundled
// cheap change left; R15 confounded it with the stripe swizzle).
// ---------------------------------------------------------------------------

#define D_COLS 1024
#define M_ROWS 4096   // x rows
#define N_ROWS 8192   // weight rows

using i32x4 = __attribute__((ext_vector_type(4))) int;

__device__ __forceinline__ void gload_lds16(const void* g, void* lds) {
  __builtin_amdgcn_global_load_lds(
      (const __attribute__((address_space(1))) uint32_t*)g,
      (__attribute__((address_space(3))) uint32_t*)lds, 16, 0, 0);
}

// One block per row (x rows 0..4095, w rows 4096..12287):
// invnorm[row] = 1/||row||, rmax[row] = max|row| * invnorm. No atomics.
__global__ __launch_bounds__(256) void rownorm_kernel(
    const float* __restrict__ x, const float* __restrict__ w,
    float* __restrict__ invnorm, float* __restrict__ rmax) {
  const int row = blockIdx.x;
  const float* a = (row < M_ROWS) ? x + (size_t)row * D_COLS
                                  : w + (size_t)(row - M_ROWS) * D_COLS;
  const float4 v = ((const float4*)a)[threadIdx.x];
  float ss = v.x * v.x + v.y * v.y + v.z * v.z + v.w * v.w;
  float mx = fmaxf(fmaxf(fabsf(v.x), fabsf(v.y)), fmaxf(fabsf(v.z), fabsf(v.w)));
#pragma unroll
  for (int off = 32; off; off >>= 1) {
    ss += __shfl_down(ss, off, 64);
    mx = fmaxf(mx, __shfl_down(mx, off, 64));
  }
  __shared__ float s_ss[4], s_mx[4];
  const int wave = threadIdx.x >> 6, lane = threadIdx.x & 63;
  if (lane == 0) { s_ss[wave] = ss; s_mx[wave] = mx; }
  __syncthreads();
  if (threadIdx.x == 0) {
    float tss = (s_ss[0] + s_ss[1]) + (s_ss[2] + s_ss[3]);
    float tmx = fmaxf(fmaxf(s_mx[0], s_mx[1]), fmaxf(s_mx[2], s_mx[3]));
    float inv = 1.0f / fmaxf(sqrtf(tss), 1e-12f);
    invnorm[row] = inv;
    rmax[row] = tmx * inv;
  }
}

// Single block: scales[0] = max(rmax[0:4096]), scales[1] = max(rmax[4096:12288])
__global__ __launch_bounds__(1024) void scale_reduce_kernel(
    const float* __restrict__ rmax, float* __restrict__ scales) {
  const int t = threadIdx.x;
  float mx = 0.f, mw = 0.f;
  for (int i = t; i < M_ROWS; i += 1024) mx = fmaxf(mx, rmax[i]);
  for (int i = t; i < N_ROWS; i += 1024) mw = fmaxf(mw, rmax[M_ROWS + i]);
#pragma unroll
  for (int off = 32; off; off >>= 1) {
    mx = fmaxf(mx, __shfl_down(mx, off, 64));
    mw = fmaxf(mw, __shfl_down(mw, off, 64));
  }
  __shared__ float smx[16], smw[16];
  const int wave = t >> 6, lane = t & 63;
  if (lane == 0) { smx[wave] = mx; smw[wave] = mw; }
  __syncthreads();
  if (t == 0) {
    float a = 0.f, b = 0.f;
#pragma unroll
    for (int i = 0; i < 16; ++i) { a = fmaxf(a, smx[i]); b = fmaxf(b, smw[i]); }
    scales[0] = a;
    scales[1] = b;
  }
}

// ---------------------------------------------------------------------------
// FUSED quantize+transpose for both tensors, one launch (384 blocks:
// 0..127 -> x, 128..383 -> w). Validated R12 image geometry: slab
// (panel Q = row>>7, ks 0..15) = 8KB at (Q*16+ks)*512 uint4; inside:
// idx = ck*128 + row_local, ck = 16B-K-chunk 0..3 (cc: ks=cc>>2, ck=cc&3).
// Coalesced 1KB reads, XOR-swizzled LDS, 256B-contiguous writes.
// ---------------------------------------------------------------------------
__global__ __launch_bounds__(256) void quant_fused_kernel(
    const float* __restrict__ x, const float* __restrict__ w,
    const float* __restrict__ invnorm, const float* __restrict__ scales,
    uint4* __restrict__ qx, uint4* __restrict__ qw) {
  __shared__ uint4 T[128][16];
  const int b = blockIdx.x;
  const float* a;
  const float* inv;
  float sc;
  uint4* img;
  int bb;
  if (b < 128) { a = x; inv = invnorm; sc = scales[0]; img = qx; bb = b; }
  else { a = w; inv = invnorm + M_ROWS; sc = scales[1]; img = qw; bb = b - 128; }
  const int t = threadIdx.x;
  const int g = bb & 3;          // cc group (16 cc's)
  const int Q = bb >> 2;         // 128-row panel
  const float s = 127.0f / sc;

  const int cc_l = t & 15;
  const int tr = t >> 4;
#pragma unroll
  for (int rc = 0; rc < 8; ++rc) {
    const int rl = rc * 16 + tr;
    const int r = Q * 128 + rl;
    const float f = inv[r] * s;
    const float4* src = (const float4*)(a + (size_t)r * D_COLS + (g * 16 + cc_l) * 16);
    unsigned pk[4];
#pragma unroll
    for (int q = 0; q < 4; ++q) {
      const float4 v = src[q];
      const int q0 = (int)rintf(v.x * f), q1 = (int)rintf(v.y * f);
      const int q2 = (int)rintf(v.z * f), q3 = (int)rintf(v.w * f);
      pk[q] = (unsigned)(q0 & 0xff) | ((unsigned)(q1 & 0xff) << 8) |
              ((unsigned)(q2 & 0xff) << 16) | ((unsigned)(q3 & 0xff) << 24);
    }
    T[rl][cc_l ^ (rl & 15)] = make_uint4(pk[0], pk[1], pk[2], pk[3]);
  }
  __syncthreads();

  const int cc_w = g * 16 + (t >> 4);    // global cc 0..63
  const int rw = t & 15;
  uint4* dst = img + (size_t)(Q * 16 + (cc_w >> 2)) * 512 + (cc_w & 3) * 128;
#pragma unroll
  for (int i = 0; i < 8; ++i) {
    const int rl = i * 16 + rw;
    dst[rl] = T[rl][(t >> 4) ^ (rl & 15)];
  }
}

// ---------------------------------------------------------------------------
// int8 GEMM (R13-exact, best measured): 256x128 tile, 4 waves (wr=wave>>1,
// wc=wave&1), per-wave 128x64 (acc[8][4] = 128 AGPR), 16 K-steps BK=64,
// ring-2 24KB bufs (48KB LDS), counted vmcnt(6), setprio on MFMA,
// launch_bounds(256,2) -> 2 blocks/CU, scalar coalesced epilogue.
// ---------------------------------------------------------------------------
__global__ __launch_bounds__(256, 2) void gemm_i8_kernel(
    const char* __restrict__ qx, const char* __restrict__ qw,
    const float* __restrict__ sx, const float* __restrict__ sw,
    float* __restrict__ out) {
  __shared__ __align__(16) char L[49152];
  const int t = threadIdx.x;
  const int wave = t >> 6, lane = t & 63;
  const int wr = wave >> 1, wc = wave & 1;
  const int rl = lane & 15, ko = lane >> 4;   // ko = 16B K-chunk 0..3

  const int fid = blockIdx.x;                  // 0..1023
  const int swz = (fid & 7) * 128 + (fid >> 3);
  const int bx = swz & 63;                     // col tile 0..63 (128 cols)
  const int by = swz >> 6;                     // row tile 0..15 (256 rows)

  const char* sa0 = qx + (size_t)(2 * by) * 16 * 8192;      // panel 2by
  const char* sa1 = qx + (size_t)(2 * by + 1) * 16 * 8192;  // panel 2by+1
  const char* sb0 = qw + (size_t)bx * 16 * 8192;

  i32x4 acc[8][4] = {};

#define ISSUE_HT(ks)                                                          \
  {                                                                           \
    const size_t so_ = (size_t)(ks) * 8192;                                   \
    char* d_ = L + ((ks) & 1) * 24576;                                        \
    gload_lds16(sa0 + so_ + wave * 2048 + lane * 16, d_ + wave * 2048);       \
    gload_lds16(sa0 + so_ + wave * 2048 + 1024 + lane * 16,                   \
                d_ + wave * 2048 + 1024);                                     \
    gload_lds16(sa1 + so_ + wave * 2048 + lane * 16, d_ + 8192 + wave * 2048);\
    gload_lds16(sa1 + so_ + wave * 2048 + 1024 + lane * 16,                   \
                d_ + 8192 + wave * 2048 + 1024);                              \
    gload_lds16(sb0 + so_ + wave * 2048 + lane * 16, d_ + 16384 + wave * 2048);\
    gload_lds16(sb0 + so_ + wave * 2048 + 1024 + lane * 16,                   \
                d_ + 16384 + wave * 2048 + 1024);                             \
  }

#define STEP(ks, VM)                                                          \
  {                                                                           \
    if ((ks) + 1 < 16) ISSUE_HT((ks) + 1);                                    \
    asm volatile("s_waitcnt vmcnt(" #VM ")" ::: "memory");                    \
    asm volatile("s_barrier" ::: "memory");                                   \
    const char* Ab_ = L + ((ks) & 1) * 24576 + wr * 8192;                     \
    const char* Bb_ = L + ((ks) & 1) * 24576 + 16384;                         \
    i32x4 af_[8], bf_[4];                                                     \
    _Pragma("unroll") for (int m_ = 0; m_ < 8; ++m_)                          \
      af_[m_] = *(const i32x4*)(Ab_ + (ko * 128 + m_ * 16 + rl) * 16);        \
    _Pragma("unroll") for (int n_ = 0; n_ < 4; ++n_)                          \
      bf_[n_] = *(const i32x4*)(Bb_ +                                         \
          (ko * 128 + wc * 64 + n_ * 16 + rl) * 16);                          \
    __builtin_amdgcn_s_setprio(1);                                            \
    _Pragma("unroll") for (int m_ = 0; m_ < 8; ++m_)                          \
      _Pragma("unroll") for (int n_ = 0; n_ < 4; ++n_)                        \
        acc[m_][n_] = __builtin_amdgcn_mfma_i32_16x16x64_i8(                  \
            af_[m_], bf_[n_], acc[m_][n_], 0, 0, 0);                          \
    __builtin_amdgcn_s_setprio(0);                                            \
    asm volatile("s_barrier" ::: "memory");                                   \
  }

  ISSUE_HT(0);

#pragma unroll 1
  for (int ks = 0; ks < 15; ++ks) STEP(ks, 6);
  STEP(15, 0);
#undef STEP
#undef ISSUE_HT

  const float cs = sx[0] * sw[0] * (1.0f / 16129.0f);  // (sx/127)*(sw/127)
  const int rowBase = by * 256 + wr * 128;
  const int colBase = bx * 128 + wc * 64;
#pragma unroll
  for (int m = 0; m < 8; ++m) {
    const int row = rowBase + m * 16 + ko * 4;
#pragma unroll
    for (int n = 0; n < 4; ++n) {
      const int col = colBase + n * 16 + rl;
#pragma unroll
      for (int j = 0; j < 4; ++j)
        out[(size_t)(row + j) * N_ROWS + col] = 1.0f - (float)acc[m][n][j] * cs;
    }
  }
}

extern "C" void kernel_launch(void* const* d_in, const int* in_sizes, int n_in,
                              void* d_out, int out_size, void* d_ws, size_t ws_size,
                              hipStream_t stream) {
  const float* x = (const float*)d_in[0];   // [4096, 1024]
  const float* w = (const float*)d_in[1];   // [8192, 1024]
  float* out = (float*)d_out;               // [4096, 8192]

  char* ws = (char*)d_ws;
  char* qx = ws;                                        // 4 MB blocked image
  char* qw = ws + (size_t)M_ROWS * D_COLS;              // 8 MB blocked image
  float* invnorm = (float*)(ws + (size_t)(M_ROWS + N_ROWS) * D_COLS);  // [12288]
  float* rmax = invnorm + (M_ROWS + N_ROWS);            // [12288]
  float* scales = rmax + (M_ROWS + N_ROWS);             // [0]=sx, [1]=sw

  rownorm_kernel<<<M_ROWS + N_ROWS, 256, 0, stream>>>(x, w, invnorm, rmax);
  scale_reduce_kernel<<<1, 1024, 0, stream>>>(rmax, scales);

  quant_fused_kernel<<<384, 256, 0, stream>>>(
      x, w, invnorm, scales, (uint4*)qx, (uint4*)qw);

  gemm_i8_kernel<<<dim3(1024), 256, 0, stream>>>(qx, qw, &scales[0], &scales[1], out);
}